// Round 1
// baseline (98010.828 us; speedup 1.0000x reference)
//
#include <hip/hip_runtime.h>
#include <math.h>

// ---------------- problem sizes ----------------
#define NN   2048   // source length
#define TLEN 2048   // target length
#define TTAG 64     // tags
#define VOC  50257
#define GW   64     // attention worker blocks
#define CHK  32     // source rows per worker
static_assert(GW * CHK == NN, "chunking");

// ---------------- workspace layout (float units) ----------------
#define OFF_XF    0                          // NN*400  x@Wih.T + b (fwd enc)
#define OFF_XB    (OFF_XF  + NN*400)         // NN*400  (bwd enc)
#define OFF_TGX   (OFF_XB  + NN*400)         // TTAG*400 (tag enc)
#define OFF_PEW   (OFF_TGX + TTAG*400)       // TLEN*400 pe@Wih_pe.T + dec_b
#define OFF_ENC   (OFF_PEW + TLEN*400)       // NN*200
#define OFF_W1DT  (OFF_ENC + NN*200)         // NN*100
#define OFF_TAGV  (OFF_W1DT+ NN*100)         // TTAG*100
#define OFF_TGW1  (OFF_TAGV+ TTAG*100)       // TTAG*100 tag_w1dt
#define OFF_TGW   (OFF_TGW1+ TTAG*100)       // TTAG*400 tagv@Wih_tag.T
#define OFF_HOUT  (OFF_TGW + TTAG*400)       // TLEN*100 decoder hn
#define OFF_SC    (OFF_HOUT+ TLEN*100)       // 2*NN raw scores (dbuf)
#define OFF_REC   (OFF_SC  + 2*NN)           // 2*GW*128 worker records (dbuf)
#define OFF_QA    (OFF_REC + 2*GW*128)       // 2*128 query a2+a3 (dbuf)
#define OFF_FLG   (OFF_QA  + 2*128)          // 128 ints: [0]=qflag, [1+w]=wflag
#define OFF_PB    (OFF_FLG + 128)            // 128*2*16*4 loss partials

// ---------------- helpers ----------------
__device__ __forceinline__ float sigf(float x){ return 1.0f/(1.0f+__expf(-x)); }
__device__ __forceinline__ unsigned short f2b(float x){
  unsigned b=__float_as_uint(x);
  return (unsigned short)((b + 0x7fffu + ((b>>16)&1u))>>16);
}
__device__ __forceinline__ unsigned pk2(float a,float b){ return (unsigned)f2b(a) | ((unsigned)f2b(b)<<16); }
__device__ __forceinline__ float blo(unsigned u){ return __uint_as_float(u<<16); }
__device__ __forceinline__ float bhi(unsigned u){ return __uint_as_float(u&0xffff0000u); }

__device__ __forceinline__ float aldf(float* p){ return __hip_atomic_load(p,__ATOMIC_RELAXED,__HIP_MEMORY_SCOPE_AGENT); }
__device__ __forceinline__ void  astf(float* p,float v){ __hip_atomic_store(p,v,__ATOMIC_RELAXED,__HIP_MEMORY_SCOPE_AGENT); }
__device__ __forceinline__ int   aldi(int* p){ return __hip_atomic_load(p,__ATOMIC_RELAXED,__HIP_MEMORY_SCOPE_AGENT); }
__device__ __forceinline__ void  asti(int* p,int v){ __hip_atomic_store(p,v,__ATOMIC_RELAXED,__HIP_MEMORY_SCOPE_AGENT); }

// ---------------- kInit: zero sync flags (every launch) ----------------
__global__ void kInit(float* ws){
  int* f = (int*)(ws + OFF_FLG);
  if (threadIdx.x < 128) f[threadIdx.x] = 0;
}

// ---------------- kPrep: all input-side GEMVs (parallel) ----------------
__global__ __launch_bounds__(512) void kPrep(
    const int* src, const int* tag, const int* oid,
    const float* emb_char, const float* emb_tag,
    const float* fWih, const float* fb,
    const float* bWih, const float* bb,
    const float* tWih, const float* tb,
    const float* dWih, const float* db, float* ws)
{
  int r = blockIdx.x, j = threadIdx.x;
  if (j >= 400) return;
  if (r < NN) {
    const float* e = emb_char + (size_t)src[r]*32;
    const float* Wr = fWih + j*32;
    float a = fb[j];
    #pragma unroll
    for (int q=0;q<32;q++) a += e[q]*Wr[q];
    ws[OFF_XF + r*400 + j] = a;
  } else if (r < 2*NN) {
    int n = r - NN;
    const float* e = emb_char + (size_t)src[n]*32;
    const float* Wr = bWih + j*32;
    float a = bb[j];
    #pragma unroll
    for (int q=0;q<32;q++) a += e[q]*Wr[q];
    ws[OFF_XB + n*400 + j] = a;
  } else if (r < 2*NN + TTAG) {
    int s = r - 2*NN;
    const float* e = emb_tag + (size_t)tag[s]*32;
    const float* Wr = tWih + j*32;
    float a = tb[j];
    #pragma unroll
    for (int q=0;q<32;q++) a += e[q]*Wr[q];
    ws[OFF_TGX + s*400 + j] = a;
  } else {
    int t = r - (2*NN + TTAG);
    int pid = (t==0) ? 0 : oid[t-1];
    const float* e = emb_char + (size_t)pid*32;
    const float* Wr = dWih + (size_t)j*332 + 300;
    float a = db[j];
    #pragma unroll
    for (int q=0;q<32;q++) a += e[q]*Wr[q];
    ws[OFF_PEW + t*400 + j] = a;
  }
}

// ---------------- kEnc: sequential LSTM scans (3 independent blocks) ----------------
struct EncShared {
  float tvs[TTAG*100];
  float sa [TTAG*64];
  float hbuf[100];
  float zbuf[400];
};

__device__ void lstm_block(const float* Whh, const float* xbase, float* ws,
                           int reverse, int col, EncShared* sh)
{
  int tid = threadIdx.x;
  float whh[100];
  if (tid < 400){
    #pragma unroll
    for (int k=0;k<100;k++) whh[k] = Whh[tid*100+k];
  }
  float c = 0.f;
  if (tid < 100) sh->hbuf[tid] = 0.f;
  __syncthreads();
  for (int i=0;i<NN;i++){
    int n = reverse ? (NN-1-i) : i;
    if (tid < 400){
      float z = xbase[n*400+tid];
      #pragma unroll 10
      for (int k=0;k<100;k++) z += whh[k]*sh->hbuf[k];
      sh->zbuf[tid] = z;
    }
    __syncthreads();
    if (tid < 100){
      float zi=sh->zbuf[tid], zf=sh->zbuf[tid+100], zg=sh->zbuf[tid+200], zo=sh->zbuf[tid+300];
      c = sigf(zf)*c + sigf(zi)*tanhf(zg);
      float h = sigf(zo)*tanhf(c);
      sh->hbuf[tid] = h;
      ws[OFF_ENC + n*200 + col + tid] = h;
    }
    __syncthreads();
  }
}

__global__ __launch_bounds__(512) void kEnc(
    const float* fWhh, const float* bWhh, const float* tWhh,
    const float* taw1, const float* dWih, float* ws)
{
  __shared__ EncShared sh;
  int b = blockIdx.x, tid = threadIdx.x;
  if (b == 0){ lstm_block(fWhh, ws+OFF_XF, ws, 0, 0,   &sh); return; }
  if (b == 1){ lstm_block(bWhh, ws+OFF_XB, ws, 1, 100, &sh); return; }

  // ---- block 2: tag LSTM + self-attn + tagv-derived tables ----
  {
    float whh[100];
    if (tid<400){
      #pragma unroll
      for (int k=0;k<100;k++) whh[k] = tWhh[tid*100+k];
    }
    float c = 0.f;
    if (tid<100) sh.hbuf[tid] = 0.f;
    __syncthreads();
    for (int s=0;s<TTAG;s++){
      if (tid<400){
        float z = ws[OFF_TGX + s*400 + tid];
        #pragma unroll 10
        for (int k=0;k<100;k++) z += whh[k]*sh.hbuf[k];
        sh.zbuf[tid] = z;
      }
      __syncthreads();
      if (tid<100){
        float zi=sh.zbuf[tid], zf=sh.zbuf[tid+100], zg=sh.zbuf[tid+200], zo=sh.zbuf[tid+300];
        c = sigf(zf)*c + sigf(zi)*tanhf(zg);
        float h = sigf(zo)*tanhf(c);
        sh.hbuf[tid] = h;
        sh.tvs[s*100+tid] = h;
      }
      __syncthreads();
    }
  }
  // self-attn logits
  for (int idx=tid; idx<TTAG*TTAG; idx+=512){
    int s=idx>>6, t2=idx&63;
    float a=0.f;
    #pragma unroll 10
    for (int h=0;h<100;h++) a += sh.tvs[s*100+h]*sh.tvs[t2*100+h];
    sh.sa[idx]=a;
  }
  __syncthreads();
  if (tid<TTAG){
    float m=-1e30f;
    for (int t2=0;t2<64;t2++) m = fmaxf(m, sh.sa[tid*64+t2]);
    float sum=0.f;
    for (int t2=0;t2<64;t2++){ float e=__expf(sh.sa[tid*64+t2]-m); sh.sa[tid*64+t2]=e; sum+=e; }
    float r=1.f/sum;
    for (int t2=0;t2<64;t2++) sh.sa[tid*64+t2]*=r;
  }
  __syncthreads();
  // tagv[t2][h] = tv[t2][h] + sum_s tv[s][h]*sa[s][t2]
  float tvloc[13]; int cnt=0;
  for (int idx=tid; idx<TTAG*100; idx+=512){
    int t2=idx/100, hh=idx%100;
    float a = sh.tvs[t2*100+hh];
    for (int s=0;s<64;s++) a += sh.tvs[s*100+hh]*sh.sa[s*64+t2];
    tvloc[cnt++]=a;
    ws[OFF_TAGV+idx]=a;
  }
  __syncthreads();
  float* tagvs = sh.sa;  // reuse (sa no longer needed)
  cnt=0;
  for (int idx=tid; idx<TTAG*100; idx+=512) tagvs[idx]=tvloc[cnt++];
  __syncthreads();
  // tag_w1dt[s][k] = tagv[s]·tag_attn_w1[k]
  for (int idx=tid; idx<TTAG*100; idx+=512){
    int s=idx/100, k=idx%100;
    float a=0.f;
    #pragma unroll 10
    for (int h=0;h<100;h++) a += tagvs[s*100+h]*taw1[k*100+h];
    ws[OFF_TGW1+idx]=a;
  }
  // TGW[s][j] = tagv[s]·dec_Wih[j,200:300]
  for (int idx=tid; idx<TTAG*400; idx+=512){
    int s=idx/400, j=idx%400;
    const float* Wr = dWih + (size_t)j*332 + 200;
    float a=0.f;
    #pragma unroll 10
    for (int h=0;h<100;h++) a += tagvs[s*100+h]*Wr[h];
    ws[OFF_TGW+idx]=a;
  }
}

// ---------------- kMid: w1dt = enc @ attn_w1.T ----------------
__global__ void kMid(const float* aw1, float* ws){
  __shared__ float er[200];
  int n=blockIdx.x, tid=threadIdx.x;
  for (int i=tid;i<200;i+=128) er[i]=ws[OFF_ENC+n*200+i];
  __syncthreads();
  if (tid<100){
    const float* Wr = aw1 + tid*200;
    float a=0.f;
    #pragma unroll 8
    for (int d=0;d<200;d++) a += er[d]*Wr[d];
    ws[OFF_W1DT + n*100 + tid]=a;
  }
}

// ---------------- kDec: persistent controller/worker decoder ----------------
struct CtrlS {
  unsigned aw2[100*100];   // attn_w2 bf16 pairs [k][d/2]
  unsigned tw1[TTAG*50];   // tag_w1dt bf16 pairs [s][k/2]
  float tav[100];
  float h[100], c[100], tc[100], tsa[100];
  float ns[200];
  float u[TTAG], taw[TTAG];
  float zpre[400];
  float ctx[200];
  float mw[GW], Sw[GW], avv[GW], scl[GW];
  int   ai[GW];
  float M, S; int ami;
  float prev[5];
  float el[200];
};
struct WrkS {
  float w1[CHK*100];
  float enc[CHK*200];
  float av[100], a23[100];
  float srow[CHK], e[CHK];
  float ctxp[200];
  float hdr[4];
};
union DecU { CtrlS c; WrkS w; };

__global__ __launch_bounds__(512) void kDec(
    const float* dWhh, const float* dWih,
    const float* aw2, const float* aw3, const float* av,
    const float* taw2, const float* tav, float* ws)
{
  __shared__ DecU sm;
  const int tid = threadIdx.x;
  const int bid = blockIdx.x;
  int* flg = (int*)(ws + OFF_FLG);

  if (bid == 0) {
    // =========== CONTROLLER ===========
    CtrlS& s = sm.c;
    // per-thread register-resident weights (bf16 packed)
    unsigned wihc[100];  // dec_Wih[j,0:200], thread j<400
    unsigned whhr[50];   // dec_Whh[j,:],     thread j<400
    unsigned tw2r[25];   // tag_attn_w2[k, (tid&3)*50 : +50], 4 thr per k
    unsigned tgvr[8];    // tagv[soff..soff+16][hh], 4 thr per hh
    if (tid < 400){
      #pragma unroll
      for (int i=0;i<100;i++) wihc[i] = pk2(dWih[(size_t)tid*332+2*i], dWih[(size_t)tid*332+2*i+1]);
      #pragma unroll
      for (int i=0;i<50;i++)  whhr[i] = pk2(dWhh[tid*100+2*i], dWhh[tid*100+2*i+1]);
      int k = tid>>2, off = (tid&3)*50;
      #pragma unroll
      for (int i=0;i<25;i++)  tw2r[i] = pk2(taw2[k*200+off+2*i], taw2[k*200+off+2*i+1]);
      int hh = tid>>2, soff = (tid&3)*16;
      #pragma unroll
      for (int i=0;i<8;i++)   tgvr[i] = pk2(ws[OFF_TAGV+(soff+2*i)*100+hh], ws[OFF_TAGV+(soff+2*i+1)*100+hh]);
    }
    for (int i=tid;i<100*100;i+=512){ int k=i/100,d2=i%100; s.aw2[i]=pk2(aw2[k*200+2*d2], aw2[k*200+2*d2+1]); }
    for (int i=tid;i<TTAG*50;i+=512){ int ss=i/50,k2=i%50; s.tw1[i]=pk2(ws[OFF_TGW1+ss*100+2*k2], ws[OFF_TGW1+ss*100+2*k2+1]); }
    if (tid<100) s.tav[tid]=tav[tid];
    if (tid<5)   s.prev[tid]=0.f;
    if (tid<200) s.el[tid]=ws[OFF_ENC + 2047*200 + tid];
    __syncthreads();
    // h0,c0: z0 = ENCW[2047] + TGW[63] + PEW[0] (ENCW via wihc regs)
    if (tid<400){
      float zz = ws[OFF_TGW + 63*400 + tid] + ws[OFF_PEW + tid];
      #pragma unroll
      for (int i=0;i<100;i++){ unsigned u=wihc[i]; zz += s.el[2*i]*blo(u) + s.el[2*i+1]*bhi(u); }
      s.zpre[tid]=zz;
    }
    __syncthreads();
    if (tid<100){
      float zi=s.zpre[tid], zf=s.zpre[tid+100], zg=s.zpre[tid+200], zo=s.zpre[tid+300];
      float cc = sigf(zi)*tanhf(zg);           // c was 0
      s.c[tid]=cc;
      s.h[tid]=sigf(zo)*tanhf(cc);
    }
    __syncthreads();

    for (int t=0; t<TLEN; ++t){
      // ---- C1: tag attention + query ----
      if (tid<400){ // tsa[k] = state · tag_attn_w2[k]
        int k=tid>>2, off=(tid&3)*50;
        const float* sb = (off<100)? (s.h+off) : (s.c+(off-100));
        float acc=0.f;
        #pragma unroll
        for (int i=0;i<25;i++){ unsigned u=tw2r[i]; acc += sb[2*i]*blo(u) + sb[2*i+1]*bhi(u); }
        acc += __shfl_xor(acc,1,4); acc += __shfl_xor(acc,2,4);
        if ((tid&3)==0) s.tsa[k]=acc;
      }
      __syncthreads();
      { // tag scores u[s'] = sum_k tanh(tw1+tsa)*tav
        int sp=tid>>3, l=tid&7;
        float acc=0.f;
        for (int k=l;k<100;k+=8){
          unsigned u=s.tw1[sp*50+(k>>1)];
          float w1v=(l&1)? bhi(u) : blo(u);
          acc += tanhf(w1v + s.tsa[k]) * s.tav[k];
        }
        acc += __shfl_xor(acc,1,8); acc += __shfl_xor(acc,2,8); acc += __shfl_xor(acc,4,8);
        if (l==0) s.u[sp]=acc;
      }
      __syncthreads();
      if (tid<64){ // softmax over 64 tags
        float v=s.u[tid], m=v;
        for (int d=1;d<64;d<<=1) m=fmaxf(m,__shfl_xor(m,d,64));
        float e=__expf(v-m), ssum=e;
        for (int d=1;d<64;d<<=1) ssum+=__shfl_xor(ssum,d,64);
        s.taw[tid]=e/ssum;
      }
      __syncthreads();
      if (tid<400){ // tag_ctx[hh] = taw · tagv[:,hh]
        int hh=tid>>2, soff=(tid&3)*16;
        float acc=0.f;
        #pragma unroll
        for (int i=0;i<8;i++){ unsigned u=tgvr[i]; acc += s.taw[soff+2*i]*blo(u) + s.taw[soff+2*i+1]*bhi(u); }
        acc += __shfl_xor(acc,1,4); acc += __shfl_xor(acc,2,4);
        if ((tid&3)==0) s.tc[hh]=acc;
      }
      __syncthreads();
      if (tid<200) s.ns[tid] = ((tid<100)? s.h[tid] : s.c[tid-100]) + s.tc[tid%100];
      __syncthreads();
      if (tid<400){ // a2[k] + a3[k] -> publish
        int k=tid>>2, off=(tid&3)*50;
        float acc=0.f;
        #pragma unroll
        for (int i=0;i<25;i++){ unsigned u=s.aw2[k*100+(off>>1)+i]; acc += s.ns[off+2*i]*blo(u) + s.ns[off+2*i+1]*bhi(u); }
        acc += __shfl_xor(acc,1,4); acc += __shfl_xor(acc,2,4);
        if ((tid&3)==0){
          float a3=0.f;
          #pragma unroll
          for (int i=0;i<5;i++) a3 += s.prev[i]*aw3[k*5+i];
          astf(ws+OFF_QA+(t&1)*128+k, acc+a3);
        }
      }
      __threadfence(); __syncthreads();
      if (tid==0) asti(flg, t+1);

      // ---- overlap window: zpre = h@Whh + PEW[t] + taw@TGW ----
      if (tid<400){
        float zz = ws[OFF_PEW + t*400 + tid];
        #pragma unroll
        for (int i=0;i<50;i++){ unsigned u=whhr[i]; zz += s.h[2*i]*blo(u) + s.h[2*i+1]*bhi(u); }
        for (int ss=0;ss<TTAG;ss++) zz += s.taw[ss]*ws[OFF_TGW+ss*400+tid];
        s.zpre[tid]=zz;
      }

      // ---- C2: wait workers, reduce, cell ----
      {
        int ok;
        do { ok = (tid<GW)? (aldi(flg+1+tid) >= t+1) : 1; } while (__syncthreads_count(ok) < 512);
      }
      unsigned stash[16];
      if (tid<400){
        int dw=tid>>2, s4=tid&3;
        #pragma unroll
        for (int i=0;i<16;i++)
          stash[i]=(unsigned)aldi((int*)(ws+OFF_REC+(t&1)*GW*128+(s4*16+i)*128+dw));
      }
      if (tid>=400 && tid<400+GW){
        int wkr=tid-400;
        float* rp = ws+OFF_REC+(t&1)*GW*128+wkr*128;
        s.mw[wkr]=aldf(rp+100); s.Sw[wkr]=aldf(rp+101); s.avv[wkr]=aldf(rp+102);
        s.ai[wkr]=aldi((int*)rp+103);
      }
      __syncthreads();
      if (tid<GW){
        float m=s.mw[tid];
        for (int d=1;d<64;d<<=1) m=fmaxf(m,__shfl_xor(m,d,64));
        float sc=__expf(s.mw[tid]-m); s.scl[tid]=sc;
        float Ss=s.Sw[tid]*sc;
        for (int d=1;d<64;d<<=1) Ss+=__shfl_xor(Ss,d,64);
        float bv=s.avv[tid]; int bi=s.ai[tid];
        for (int d=1;d<64;d<<=1){
          float ov=__shfl_xor(bv,d,64); int oi=__shfl_xor(bi,d,64);
          if (ov>bv || (ov==bv && oi<bi)){ bv=ov; bi=oi; }
        }
        if (tid==0){ s.M=m; s.S=Ss; s.ami=bi; }
      }
      __syncthreads();
      // issue new_prev loads early (consumed after gates)
      float nraw=0.f; int ii=tid-96;
      if (ii>=0 && ii<5){
        int st = s.ami-1; st = st<0?0:st; st = st>NN-6?NN-6:st;
        nraw = aldf(ws+OFF_SC+(t&1)*NN+st+ii);
      }
      if (tid<400){ // ctx = sum_w scl*ctxp / S
        float rS = 1.0f/s.S;
        int s4=tid&3;
        float c0=0.f,c1=0.f;
        #pragma unroll
        for (int i=0;i<16;i++){
          float sc=s.scl[s4*16+i];
          c0 += blo(stash[i])*sc; c1 += bhi(stash[i])*sc;
        }
        c0 += __shfl_xor(c0,1,4); c0 += __shfl_xor(c0,2,4);
        c1 += __shfl_xor(c1,1,4); c1 += __shfl_xor(c1,2,4);
        if (s4==0){ int dw=tid>>2; s.ctx[2*dw]=c0*rS; s.ctx[2*dw+1]=c1*rS; }
      }
      __syncthreads();
      if (tid<400){ // z = zpre + ctx·Wih_ctx[j]
        float zz=s.zpre[tid];
        #pragma unroll
        for (int i=0;i<100;i++){ unsigned u=wihc[i]; zz += s.ctx[2*i]*blo(u) + s.ctx[2*i+1]*bhi(u); }
        s.zpre[tid]=zz;
      }
      __syncthreads();
      if (tid<100){
        float zi=s.zpre[tid], zf=s.zpre[tid+100], zg=s.zpre[tid+200], zo=s.zpre[tid+300];
        float cc = sigf(zf)*s.c[tid] + sigf(zi)*tanhf(zg);
        float hh = sigf(zo)*tanhf(cc);
        s.c[tid]=cc; s.h[tid]=hh;
        ws[OFF_HOUT + t*100 + tid] = hh;
      }
      if (ii>=0 && ii<5) s.prev[ii] = __expf(nraw - s.M)/s.S;
      __syncthreads();
    }
  } else {
    // =========== WORKER ===========
    WrkS& s = sm.w;
    const int w = bid-1;
    for (int i=tid;i<CHK*100;i+=512) s.w1[i]  = ws[OFF_W1DT + w*CHK*100 + i];
    for (int i=tid;i<CHK*200;i+=512) s.enc[i] = ws[OFF_ENC  + w*CHK*200 + i];
    if (tid<100) s.av[tid]=av[tid];
    __syncthreads();

    for (int t=0;t<TLEN;++t){
      { // wait for query
        int ok;
        do { ok = tid? 1 : (aldi(flg) >= t+1); } while (__syncthreads_count(ok) < 512);
      }
      if (tid<100) s.a23[tid] = aldf(ws+OFF_QA+(t&1)*128+tid);
      __syncthreads();
      { // scores for own rows: 16 lanes per row
        int r=tid>>4, l=tid&15;
        float acc=0.f;
        for (int k=l;k<100;k+=16) acc += tanhf(s.w1[r*100+k] + s.a23[k]) * s.av[k];
        acc += __shfl_xor(acc,1,16); acc += __shfl_xor(acc,2,16);
        acc += __shfl_xor(acc,4,16); acc += __shfl_xor(acc,8,16);
        if (l==0) s.srow[r]=acc;
      }
      __syncthreads();
      if (tid<CHK) astf(ws+OFF_SC+(t&1)*NN + w*CHK + tid, s.srow[tid]);
      if (tid<32){ // local softmax stats + argmax
        float v=s.srow[tid], m=v;
        for (int d=1;d<32;d<<=1) m=fmaxf(m,__shfl_xor(m,d,32));
        float e=__expf(v-m); s.e[tid]=e;
        float Ss=e;
        for (int d=1;d<32;d<<=1) Ss+=__shfl_xor(Ss,d,32);
        float bv=v; int bi=w*CHK+tid;
        for (int d=1;d<32;d<<=1){
          float ov=__shfl_xor(bv,d,32); int oi=__shfl_xor(bi,d,32);
          if (ov>bv || (ov==bv && oi<bi)){ bv=ov; bi=oi; }
        }
        if (tid==0){ s.hdr[0]=m; s.hdr[1]=Ss; s.hdr[2]=bv; ((int*)s.hdr)[3]=bi; }
      }
      __syncthreads();
      if (tid<400){ // ctx partial over own rows
        int d=tid>>1, hf=tid&1;
        float acc=0.f;
        #pragma unroll
        for (int r2=0;r2<16;r2++){ int rr=hf*16+r2; acc += s.e[rr]*s.enc[rr*200+d]; }
        acc += __shfl_xor(acc,1,2);
        if (hf==0) s.ctxp[d]=acc;
      }
      __syncthreads();
      float* rp = ws+OFF_REC+(t&1)*GW*128 + w*128;
      if (tid<100) asti((int*)rp+tid, (int)pk2(s.ctxp[2*tid], s.ctxp[2*tid+1]));
      if (tid>=100 && tid<103) astf(rp+tid, s.hdr[tid-100]);
      if (tid==103) asti((int*)rp+103, ((int*)s.hdr)[3]);
      __threadfence(); __syncthreads();
      if (tid==0) asti(flg+1+w, t+1);
    }
  }
}

// ---------------- kLoss: parallel logits + log-softmax over V ----------------
__global__ __launch_bounds__(256) void kLoss(const float* outW, const float* outb,
                                             const int* oid, float* ws)
{
  const int b=blockIdx.x, tid=threadIdx.x;
  const int tile=b>>1, hf=b&1, t0=tile*16;
  __shared__ float s_hn[16*100];
  __shared__ int   s_oid[16];
  __shared__ float red[4][16][3];
  for (int i=tid;i<1600;i+=256) s_hn[i]=ws[OFF_HOUT + t0*100 + i];
  if (tid<16) s_oid[tid]=oid[t0+tid];
  __syncthreads();
  const int VSPLIT = 25129;
  int vbeg = hf? VSPLIT : 0;
  int vend = hf? VOC : VSPLIT;
  float rm[16], rs[16], ol[16];
  #pragma unroll
  for (int tt=0;tt<16;tt++){ rm[tt]=-1e30f; rs[tt]=0.f; ol[tt]=-1e30f; }
  for (int v=vbeg+tid; v<vend; v+=256){
    const float4* wr = (const float4*)(outW + (size_t)v*100);
    float acc[16];
    #pragma unroll
    for (int tt=0;tt<16;tt++) acc[tt]=0.f;
    #pragma unroll 5
    for (int q=0;q<25;q++){
      float4 wv = wr[q];
      #pragma unroll
      for (int tt=0;tt<16;tt++){
        float4 hv = *(const float4*)(s_hn + tt*100 + q*4);
        acc[tt] += wv.x*hv.x + wv.y*hv.y + wv.z*hv.z + wv.w*hv.w;
      }
    }
    float bb = outb[v];
    #pragma unroll
    for (int tt=0;tt<16;tt++){
      float lg = acc[tt] + bb;
      if (v == s_oid[tt]) ol[tt] = fmaxf(ol[tt], lg);
      if (lg <= rm[tt]) rs[tt] += __expf(lg - rm[tt]);
      else { rs[tt] = rs[tt]*__expf(rm[tt]-lg) + 1.0f; rm[tt]=lg; }
    }
  }
  int wv2=tid>>6, ln=tid&63;
  #pragma unroll
  for (int tt=0;tt<16;tt++){
    float m=rm[tt], sv=rs[tt], o=ol[tt];
    for (int d=1;d<64;d<<=1){
      float om=__shfl_xor(m,d,64), os=__shfl_xor(sv,d,64), oo=__shfl_xor(o,d,64);
      float M2=fmaxf(m,om);
      sv = sv*__expf(m-M2) + os*__expf(om-M2);
      m=M2; o=fmaxf(o,oo);
    }
    if (ln==0){ red[wv2][tt][0]=m; red[wv2][tt][1]=sv; red[wv2][tt][2]=o; }
  }
  __syncthreads();
  if (tid<16){
    float M=-1e30f;
    for (int q=0;q<4;q++) M=fmaxf(M,red[q][tid][0]);
    float S=0.f, O=-1e30f;
    for (int q=0;q<4;q++){ S += red[q][tid][1]*__expf(red[q][tid][0]-M); O=fmaxf(O,red[q][tid][2]); }
    float* pb = ws + OFF_PB + (((tile*2)+hf)*16 + tid)*4;
    pb[0]=M; pb[1]=S; pb[2]=O;
  }
}

// ---------------- kFinal: combine halves, sum, scale ----------------
__global__ void kFinal(const float* weight, float* ws, float* out){
  __shared__ float red[256];
  int tid=threadIdx.x;
  float acc=0.f;
  for (int t=tid;t<TLEN;t+=256){
    int tile=t>>4, tt=t&15;
    const float* p0 = ws + OFF_PB + ((tile*2+0)*16+tt)*4;
    const float* p1 = ws + OFF_PB + ((tile*2+1)*16+tt)*4;
    float M=fmaxf(p0[0],p1[0]);
    float S=p0[1]*__expf(p0[0]-M) + p1[1]*__expf(p1[0]-M);
    float O=fmaxf(p0[2],p1[2]);
    acc += (M + logf(S)) - O;    // lt = lse - logit[oid]
  }
  red[tid]=acc; __syncthreads();
  for (int d=128; d>0; d>>=1){
    if (tid<d) red[tid]+=red[tid+d];
    __syncthreads();
  }
  if (tid==0) out[0]=red[0]*weight[0];
}

// ---------------- launch ----------------
extern "C" void kernel_launch(void* const* d_in, const int* in_sizes, int n_in,
                              void* d_out, int out_size, void* d_ws, size_t ws_size,
                              hipStream_t stream) {
  const int*   src      = (const int*)  d_in[0];
  const int*   tag      = (const int*)  d_in[1];
  const int*   oid      = (const int*)  d_in[2];
  const float* weight   = (const float*)d_in[3];
  const float* emb_char = (const float*)d_in[4];
  const float* emb_tag  = (const float*)d_in[5];
  const float* fWih=(const float*)d_in[6],  *fWhh=(const float*)d_in[7],  *fb=(const float*)d_in[8];
  const float* bWih=(const float*)d_in[9],  *bWhh=(const float*)d_in[10], *bb=(const float*)d_in[11];
  const float* tWih=(const float*)d_in[12], *tWhh=(const float*)d_in[13], *tb=(const float*)d_in[14];
  const float* dWih=(const float*)d_in[15], *dWhh=(const float*)d_in[16], *db=(const float*)d_in[17];
  const float* aw1 =(const float*)d_in[18], *aw2=(const float*)d_in[19];
  const float* aw3 =(const float*)d_in[20], *av =(const float*)d_in[21];
  const float* taw1=(const float*)d_in[22], *taw2=(const float*)d_in[23], *tavv=(const float*)d_in[24];
  const float* outW=(const float*)d_in[25], *outb=(const float*)d_in[26];
  float* ws  = (float*)d_ws;
  float* out = (float*)d_out;

  kInit<<<1,128,0,stream>>>(ws);
  kPrep<<<2*NN+TTAG+TLEN, 512, 0, stream>>>(src,tag,oid,emb_char,emb_tag,
                                            fWih,fb,bWih,bb,tWih,tb,dWih,db,ws);
  kEnc<<<3,512,0,stream>>>(fWhh,bWhh,tWhh,taw1,dWih,ws);
  kMid<<<NN,128,0,stream>>>(aw1,ws);
  kDec<<<1+GW,512,0,stream>>>(dWhh,dWih,aw2,aw3,av,taw2,tavv,ws);
  kLoss<<<256,256,0,stream>>>(outW,outb,oid,ws);
  kFinal<<<1,256,0,stream>>>(weight,ws,out);
}

// Round 2
// 78631.201 us; speedup vs baseline: 1.2465x; 1.2465x over previous
//
#include <hip/hip_runtime.h>
#include <math.h>

// ---------------- problem sizes ----------------
#define NN   2048   // source length
#define TLEN 2048   // target length
#define TTAG 64     // tags
#define VOC  50257
#define GW   64     // attention worker blocks
#define CHK  32     // source rows per worker
static_assert(GW * CHK == NN, "chunking");

// ---------------- workspace layout (float units) ----------------
#define OFF_XF    0                          // NN*400  x@Wih.T + b (fwd enc)
#define OFF_XB    (OFF_XF  + NN*400)         // NN*400  (bwd enc)
#define OFF_TGX   (OFF_XB  + NN*400)         // TTAG*400 (tag enc)
#define OFF_PEW   (OFF_TGX + TTAG*400)       // TLEN*400 pe@Wih_pe.T + dec_b
#define OFF_ENC   (OFF_PEW + TLEN*400)       // NN*200
#define OFF_W1DT  (OFF_ENC + NN*200)         // NN*100
#define OFF_TAGV  (OFF_W1DT+ NN*100)         // TTAG*100
#define OFF_TGW1  (OFF_TAGV+ TTAG*100)       // TTAG*100 tag_w1dt
#define OFF_TGW   (OFF_TGW1+ TTAG*100)       // TTAG*400 tagv@Wih_tag.T
#define OFF_HOUT  (OFF_TGW + TTAG*400)       // TLEN*100 decoder hn
#define OFF_SC    (OFF_HOUT+ TLEN*100)       // 2*NN raw scores (dbuf)
#define OFF_REC   (OFF_SC  + 2*NN)           // 2*GW*128 worker records (dbuf)
#define OFF_QA    (OFF_REC + 2*GW*128)       // 2*128 query a2+a3 (dbuf)
#define OFF_FLG   (OFF_QA  + 2*128)          // 128 slots x 32 floats (128B spread)
                                             //   [w*32]      : query seq for worker w
                                             //   [(64+w)*32] : done seq from worker w
#define OFF_PB    (OFF_FLG + 128*32)         // loss partials

// ---------------- helpers ----------------
__device__ __forceinline__ float sigf(float x){ return 1.0f/(1.0f+__expf(-x)); }
__device__ __forceinline__ float tanhfast(float x){
  float e = __expf(2.0f*x);
  return 1.0f - 2.0f/(e+1.0f);
}
__device__ __forceinline__ unsigned short f2b(float x){
  unsigned b=__float_as_uint(x);
  return (unsigned short)((b + 0x7fffu + ((b>>16)&1u))>>16);
}
__device__ __forceinline__ unsigned pk2(float a,float b){ return (unsigned)f2b(a) | ((unsigned)f2b(b)<<16); }
__device__ __forceinline__ float blo(unsigned u){ return __uint_as_float(u<<16); }
__device__ __forceinline__ float bhi(unsigned u){ return __uint_as_float(u&0xffff0000u); }

__device__ __forceinline__ float aldf(float* p){ return __hip_atomic_load(p,__ATOMIC_RELAXED,__HIP_MEMORY_SCOPE_AGENT); }
__device__ __forceinline__ void  astf(float* p,float v){ __hip_atomic_store(p,v,__ATOMIC_RELAXED,__HIP_MEMORY_SCOPE_AGENT); }
__device__ __forceinline__ int   aldi(int* p){ return __hip_atomic_load(p,__ATOMIC_RELAXED,__HIP_MEMORY_SCOPE_AGENT); }
__device__ __forceinline__ void  asti(int* p,int v){ __hip_atomic_store(p,v,__ATOMIC_RELAXED,__HIP_MEMORY_SCOPE_AGENT); }

// Per-wave completion fence: all prior global stores (relaxed agent atomics,
// routed to the coherence point) have COMPLETED when this retires. Combined
// with __syncthreads() this orders data-stores before the flag-store without
// any L2 writeback/invalidate (which __threadfence would emit on multi-XCD).
__device__ __forceinline__ void vm0(){ asm volatile("s_waitcnt vmcnt(0)" ::: "memory"); }

// ---------------- kInit: zero sync flags (every launch) ----------------
__global__ void kInit(float* ws){
  int* f = (int*)(ws + OFF_FLG);
  for (int i=threadIdx.x; i<128*32; i+=256) f[i] = 0;
}

// ---------------- kPrep: all input-side GEMVs (parallel) ----------------
__global__ __launch_bounds__(512) void kPrep(
    const int* src, const int* tag, const int* oid,
    const float* emb_char, const float* emb_tag,
    const float* fWih, const float* fb,
    const float* bWih, const float* bb,
    const float* tWih, const float* tb,
    const float* dWih, const float* db, float* ws)
{
  int r = blockIdx.x, j = threadIdx.x;
  if (j >= 400) return;
  if (r < NN) {
    const float* e = emb_char + (size_t)src[r]*32;
    const float* Wr = fWih + j*32;
    float a = fb[j];
    #pragma unroll
    for (int q=0;q<32;q++) a += e[q]*Wr[q];
    ws[OFF_XF + r*400 + j] = a;
  } else if (r < 2*NN) {
    int n = r - NN;
    const float* e = emb_char + (size_t)src[n]*32;
    const float* Wr = bWih + j*32;
    float a = bb[j];
    #pragma unroll
    for (int q=0;q<32;q++) a += e[q]*Wr[q];
    ws[OFF_XB + n*400 + j] = a;
  } else if (r < 2*NN + TTAG) {
    int s = r - 2*NN;
    const float* e = emb_tag + (size_t)tag[s]*32;
    const float* Wr = tWih + j*32;
    float a = tb[j];
    #pragma unroll
    for (int q=0;q<32;q++) a += e[q]*Wr[q];
    ws[OFF_TGX + s*400 + j] = a;
  } else {
    int t = r - (2*NN + TTAG);
    int pid = (t==0) ? 0 : oid[t-1];
    const float* e = emb_char + (size_t)pid*32;
    const float* Wr = dWih + (size_t)j*332 + 300;
    float a = db[j];
    #pragma unroll
    for (int q=0;q<32;q++) a += e[q]*Wr[q];
    ws[OFF_PEW + t*400 + j] = a;
  }
}

// ---------------- kEnc: sequential LSTM scans (3 independent blocks) ----------------
struct EncShared {
  float tvs[TTAG*100];
  float sa [TTAG*64];
  float hbuf[100];
  float zbuf[400];
};

__device__ void lstm_block(const float* Whh, const float* xbase, float* ws,
                           int reverse, int col, EncShared* sh)
{
  int tid = threadIdx.x;
  float whh[100];
  if (tid < 400){
    #pragma unroll
    for (int k=0;k<100;k++) whh[k] = Whh[tid*100+k];
  }
  float c = 0.f;
  if (tid < 100) sh->hbuf[tid] = 0.f;
  __syncthreads();
  for (int i=0;i<NN;i++){
    int n = reverse ? (NN-1-i) : i;
    if (tid < 400){
      float z = xbase[n*400+tid];
      #pragma unroll 10
      for (int k=0;k<100;k++) z += whh[k]*sh->hbuf[k];
      sh->zbuf[tid] = z;
    }
    __syncthreads();
    if (tid < 100){
      float zi=sh->zbuf[tid], zf=sh->zbuf[tid+100], zg=sh->zbuf[tid+200], zo=sh->zbuf[tid+300];
      c = sigf(zf)*c + sigf(zi)*tanhfast(zg);
      float h = sigf(zo)*tanhfast(c);
      sh->hbuf[tid] = h;
      ws[OFF_ENC + n*200 + col + tid] = h;
    }
    __syncthreads();
  }
}

__global__ __launch_bounds__(512) void kEnc(
    const float* fWhh, const float* bWhh, const float* tWhh,
    const float* taw1, const float* dWih, float* ws)
{
  __shared__ EncShared sh;
  int b = blockIdx.x, tid = threadIdx.x;
  if (b == 0){ lstm_block(fWhh, ws+OFF_XF, ws, 0, 0,   &sh); return; }
  if (b == 1){ lstm_block(bWhh, ws+OFF_XB, ws, 1, 100, &sh); return; }

  // ---- block 2: tag LSTM + self-attn + tagv-derived tables ----
  {
    float whh[100];
    if (tid<400){
      #pragma unroll
      for (int k=0;k<100;k++) whh[k] = tWhh[tid*100+k];
    }
    float c = 0.f;
    if (tid<100) sh.hbuf[tid] = 0.f;
    __syncthreads();
    for (int s=0;s<TTAG;s++){
      if (tid<400){
        float z = ws[OFF_TGX + s*400 + tid];
        #pragma unroll 10
        for (int k=0;k<100;k++) z += whh[k]*sh.hbuf[k];
        sh.zbuf[tid] = z;
      }
      __syncthreads();
      if (tid<100){
        float zi=sh.zbuf[tid], zf=sh.zbuf[tid+100], zg=sh.zbuf[tid+200], zo=sh.zbuf[tid+300];
        c = sigf(zf)*c + sigf(zi)*tanhfast(zg);
        float h = sigf(zo)*tanhfast(c);
        sh.hbuf[tid] = h;
        sh.tvs[s*100+tid] = h;
      }
      __syncthreads();
    }
  }
  // self-attn logits
  for (int idx=tid; idx<TTAG*TTAG; idx+=512){
    int s=idx>>6, t2=idx&63;
    float a=0.f;
    #pragma unroll 10
    for (int h=0;h<100;h++) a += sh.tvs[s*100+h]*sh.tvs[t2*100+h];
    sh.sa[idx]=a;
  }
  __syncthreads();
  if (tid<TTAG){
    float m=-1e30f;
    for (int t2=0;t2<64;t2++) m = fmaxf(m, sh.sa[tid*64+t2]);
    float sum=0.f;
    for (int t2=0;t2<64;t2++){ float e=__expf(sh.sa[tid*64+t2]-m); sh.sa[tid*64+t2]=e; sum+=e; }
    float r=1.f/sum;
    for (int t2=0;t2<64;t2++) sh.sa[tid*64+t2]*=r;
  }
  __syncthreads();
  // tagv[t2][h] = tv[t2][h] + sum_s tv[s][h]*sa[s][t2]
  float tvloc[13]; int cnt=0;
  for (int idx=tid; idx<TTAG*100; idx+=512){
    int t2=idx/100, hh=idx%100;
    float a = sh.tvs[t2*100+hh];
    for (int s=0;s<64;s++) a += sh.tvs[s*100+hh]*sh.sa[s*64+t2];
    tvloc[cnt++]=a;
    ws[OFF_TAGV+idx]=a;
  }
  __syncthreads();
  float* tagvs = sh.sa;  // reuse (sa no longer needed)
  cnt=0;
  for (int idx=tid; idx<TTAG*100; idx+=512) tagvs[idx]=tvloc[cnt++];
  __syncthreads();
  // tag_w1dt[s][k] = tagv[s]·tag_attn_w1[k]
  for (int idx=tid; idx<TTAG*100; idx+=512){
    int s=idx/100, k=idx%100;
    float a=0.f;
    #pragma unroll 10
    for (int h=0;h<100;h++) a += tagvs[s*100+h]*taw1[k*100+h];
    ws[OFF_TGW1+idx]=a;
  }
  // TGW[s][j] = tagv[s]·dec_Wih[j,200:300]
  for (int idx=tid; idx<TTAG*400; idx+=512){
    int s=idx/400, j=idx%400;
    const float* Wr = dWih + (size_t)j*332 + 200;
    float a=0.f;
    #pragma unroll 10
    for (int h=0;h<100;h++) a += tagvs[s*100+h]*Wr[h];
    ws[OFF_TGW+idx]=a;
  }
}

// ---------------- kMid: w1dt = enc @ attn_w1.T ----------------
__global__ void kMid(const float* aw1, float* ws){
  __shared__ float er[200];
  int n=blockIdx.x, tid=threadIdx.x;
  for (int i=tid;i<200;i+=128) er[i]=ws[OFF_ENC+n*200+i];
  __syncthreads();
  if (tid<100){
    const float* Wr = aw1 + tid*200;
    float a=0.f;
    #pragma unroll 8
    for (int d=0;d<200;d++) a += er[d]*Wr[d];
    ws[OFF_W1DT + n*100 + tid]=a;
  }
}

// ---------------- kDec: persistent controller/worker decoder ----------------
struct CtrlS {
  unsigned aw2[100*100];   // attn_w2 bf16 pairs [k][d/2]
  unsigned tw1[TTAG*50];   // tag_w1dt bf16 pairs [s][k/2]
  float tav[100];
  float h[100], c[100], tc[100], tsa[100];
  float ns[200];
  float u[TTAG], taw[TTAG];
  float zpre[400];
  float ctx[200];
  float mw[GW], Sw[GW], avv[GW], scl[GW];
  int   ai[GW];
  float M, S; int ami;
  float prev[5];
  float el[200];
};
struct WrkS {
  float w1[CHK*100];
  float enc[CHK*200];
  float av[100], a23[100];
  float srow[CHK], e[CHK];
  float ctxp[200];
  float hdr[4];
};
union DecU { CtrlS c; WrkS w; };

__global__ __launch_bounds__(512) void kDec(
    const float* dWhh, const float* dWih,
    const float* aw2, const float* aw3, const float* av,
    const float* taw2, const float* tav, float* ws)
{
  __shared__ DecU sm;
  const int tid = threadIdx.x;
  const int bid = blockIdx.x;
  int* qflg = (int*)(ws + OFF_FLG);        // [w*32]
  int* dflg = (int*)(ws + OFF_FLG) + 64*32; // [w*32]

  if (bid == 0) {
    // =========== CONTROLLER ===========
    CtrlS& s = sm.c;
    // per-thread register-resident weights (bf16 packed)
    unsigned wihc[100];  // dec_Wih[j,0:200], thread j<400
    unsigned whhr[50];   // dec_Whh[j,:],     thread j<400
    unsigned tw2r[25];   // tag_attn_w2[k, (tid&3)*50 : +50], 4 thr per k
    unsigned tgvr[8];    // tagv[soff..soff+16][hh], 4 thr per hh
    if (tid < 400){
      #pragma unroll
      for (int i=0;i<100;i++) wihc[i] = pk2(dWih[(size_t)tid*332+2*i], dWih[(size_t)tid*332+2*i+1]);
      #pragma unroll
      for (int i=0;i<50;i++)  whhr[i] = pk2(dWhh[tid*100+2*i], dWhh[tid*100+2*i+1]);
      int k = tid>>2, off = (tid&3)*50;
      #pragma unroll
      for (int i=0;i<25;i++)  tw2r[i] = pk2(taw2[k*200+off+2*i], taw2[k*200+off+2*i+1]);
      int hh = tid>>2, soff = (tid&3)*16;
      #pragma unroll
      for (int i=0;i<8;i++)   tgvr[i] = pk2(ws[OFF_TAGV+(soff+2*i)*100+hh], ws[OFF_TAGV+(soff+2*i+1)*100+hh]);
    }
    for (int i=tid;i<100*100;i+=512){ int k=i/100,d2=i%100; s.aw2[i]=pk2(aw2[k*200+2*d2], aw2[k*200+2*d2+1]); }
    for (int i=tid;i<TTAG*50;i+=512){ int ss=i/50,k2=i%50; s.tw1[i]=pk2(ws[OFF_TGW1+ss*100+2*k2], ws[OFF_TGW1+ss*100+2*k2+1]); }
    if (tid<100) s.tav[tid]=tav[tid];
    if (tid<5)   s.prev[tid]=0.f;
    if (tid<200) s.el[tid]=ws[OFF_ENC + 2047*200 + tid];
    __syncthreads();
    // h0,c0: z0 = ENCW[2047] + TGW[63] + PEW[0] (ENCW via wihc regs)
    if (tid<400){
      float zz = ws[OFF_TGW + 63*400 + tid] + ws[OFF_PEW + tid];
      #pragma unroll
      for (int i=0;i<100;i++){ unsigned u=wihc[i]; zz += s.el[2*i]*blo(u) + s.el[2*i+1]*bhi(u); }
      s.zpre[tid]=zz;
    }
    __syncthreads();
    if (tid<100){
      float zi=s.zpre[tid], zf=s.zpre[tid+100], zg=s.zpre[tid+200], zo=s.zpre[tid+300];
      float cc = sigf(zi)*tanhfast(zg);           // c was 0
      s.c[tid]=cc;
      s.h[tid]=sigf(zo)*tanhfast(cc);
    }
    __syncthreads();

    for (int t=0; t<TLEN; ++t){
      // ---- C1: tag attention + query ----
      if (tid<400){ // tsa[k] = state · tag_attn_w2[k]
        int k=tid>>2, off=(tid&3)*50;
        const float* sb = (off<100)? (s.h+off) : (s.c+(off-100));
        float acc=0.f;
        #pragma unroll
        for (int i=0;i<25;i++){ unsigned u=tw2r[i]; acc += sb[2*i]*blo(u) + sb[2*i+1]*bhi(u); }
        acc += __shfl_xor(acc,1,4); acc += __shfl_xor(acc,2,4);
        if ((tid&3)==0) s.tsa[k]=acc;
      }
      __syncthreads();
      { // tag scores u[s'] = sum_k tanh(tw1+tsa)*tav
        int sp=tid>>3, l=tid&7;
        float acc=0.f;
        for (int k=l;k<100;k+=8){
          unsigned u=s.tw1[sp*50+(k>>1)];
          float w1v=(l&1)? bhi(u) : blo(u);
          acc += tanhfast(w1v + s.tsa[k]) * s.tav[k];
        }
        acc += __shfl_xor(acc,1,8); acc += __shfl_xor(acc,2,8); acc += __shfl_xor(acc,4,8);
        if (l==0) s.u[sp]=acc;
      }
      __syncthreads();
      if (tid<64){ // softmax over 64 tags
        float v=s.u[tid], m=v;
        for (int d=1;d<64;d<<=1) m=fmaxf(m,__shfl_xor(m,d,64));
        float e=__expf(v-m), ssum=e;
        for (int d=1;d<64;d<<=1) ssum+=__shfl_xor(ssum,d,64);
        s.taw[tid]=e/ssum;
      }
      __syncthreads();
      if (tid<400){ // tag_ctx[hh] = taw · tagv[:,hh]
        int hh=tid>>2, soff=(tid&3)*16;
        float acc=0.f;
        #pragma unroll
        for (int i=0;i<8;i++){ unsigned u=tgvr[i]; acc += s.taw[soff+2*i]*blo(u) + s.taw[soff+2*i+1]*bhi(u); }
        acc += __shfl_xor(acc,1,4); acc += __shfl_xor(acc,2,4);
        if ((tid&3)==0) s.tc[hh]=acc;
      }
      __syncthreads();
      if (tid<200) s.ns[tid] = ((tid<100)? s.h[tid] : s.c[tid-100]) + s.tc[tid%100];
      __syncthreads();
      if (tid<400){ // a2[k] + a3[k] -> publish
        int k=tid>>2, off=(tid&3)*50;
        float acc=0.f;
        #pragma unroll
        for (int i=0;i<25;i++){ unsigned u=s.aw2[k*100+(off>>1)+i]; acc += s.ns[off+2*i]*blo(u) + s.ns[off+2*i+1]*bhi(u); }
        acc += __shfl_xor(acc,1,4); acc += __shfl_xor(acc,2,4);
        if ((tid&3)==0){
          float a3=0.f;
          #pragma unroll
          for (int i=0;i<5;i++) a3 += s.prev[i]*aw3[k*5+i];
          astf(ws+OFF_QA+(t&1)*128+k, acc+a3);
        }
      }
      vm0(); __syncthreads();
      if (tid<GW) asti(qflg + tid*32, t+1);

      // ---- overlap window: zpre = h@Whh + PEW[t] + taw@TGW ----
      if (tid<400){
        float zz = ws[OFF_PEW + t*400 + tid];
        #pragma unroll
        for (int i=0;i<50;i++){ unsigned u=whhr[i]; zz += s.h[2*i]*blo(u) + s.h[2*i+1]*bhi(u); }
        for (int ss=0;ss<TTAG;ss++) zz += s.taw[ss]*ws[OFF_TGW+ss*400+tid];
        s.zpre[tid]=zz;
      }

      // ---- C2: wait workers, reduce, cell ----
      {
        int seen = (tid<GW)? 0 : 1;
        do {
          if (!seen) seen = (aldi(dflg + tid*32) >= t+1);
        } while (__syncthreads_count(seen) < 512);
      }
      unsigned stash[16];
      if (tid<400){
        int dw=tid>>2, s4=tid&3;
        #pragma unroll
        for (int i=0;i<16;i++)
          stash[i]=(unsigned)aldi((int*)(ws+OFF_REC+(t&1)*GW*128+(s4*16+i)*128+dw));
      }
      if (tid>=400 && tid<400+GW){
        int wkr=tid-400;
        float* rp = ws+OFF_REC+(t&1)*GW*128+wkr*128;
        s.mw[wkr]=aldf(rp+100); s.Sw[wkr]=aldf(rp+101); s.avv[wkr]=aldf(rp+102);
        s.ai[wkr]=aldi((int*)rp+103);
      }
      __syncthreads();
      if (tid<GW){
        float m=s.mw[tid];
        for (int d=1;d<64;d<<=1) m=fmaxf(m,__shfl_xor(m,d,64));
        float sc=__expf(s.mw[tid]-m); s.scl[tid]=sc;
        float Ss=s.Sw[tid]*sc;
        for (int d=1;d<64;d<<=1) Ss+=__shfl_xor(Ss,d,64);
        float bv=s.avv[tid]; int bi=s.ai[tid];
        for (int d=1;d<64;d<<=1){
          float ov=__shfl_xor(bv,d,64); int oi=__shfl_xor(bi,d,64);
          if (ov>bv || (ov==bv && oi<bi)){ bv=ov; bi=oi; }
        }
        if (tid==0){ s.M=m; s.S=Ss; s.ami=bi; }
      }
      __syncthreads();
      // issue new_prev loads early (consumed after gates)
      float nraw=0.f; int ii=tid-96;
      if (ii>=0 && ii<5){
        int st = s.ami-1; st = st<0?0:st; st = st>NN-6?NN-6:st;
        nraw = aldf(ws+OFF_SC+(t&1)*NN+st+ii);
      }
      if (tid<400){ // ctx = sum_w scl*ctxp / S
        float rS = 1.0f/s.S;
        int s4=tid&3;
        float c0=0.f,c1=0.f;
        #pragma unroll
        for (int i=0;i<16;i++){
          float sc=s.scl[s4*16+i];
          c0 += blo(stash[i])*sc; c1 += bhi(stash[i])*sc;
        }
        c0 += __shfl_xor(c0,1,4); c0 += __shfl_xor(c0,2,4);
        c1 += __shfl_xor(c1,1,4); c1 += __shfl_xor(c1,2,4);
        if (s4==0){ int dw=tid>>2; s.ctx[2*dw]=c0*rS; s.ctx[2*dw+1]=c1*rS; }
      }
      __syncthreads();
      if (tid<400){ // z = zpre + ctx·Wih_ctx[j]
        float zz=s.zpre[tid];
        #pragma unroll
        for (int i=0;i<100;i++){ unsigned u=wihc[i]; zz += s.ctx[2*i]*blo(u) + s.ctx[2*i+1]*bhi(u); }
        s.zpre[tid]=zz;
      }
      __syncthreads();
      if (tid<100){
        float zi=s.zpre[tid], zf=s.zpre[tid+100], zg=s.zpre[tid+200], zo=s.zpre[tid+300];
        float cc = sigf(zf)*s.c[tid] + sigf(zi)*tanhfast(zg);
        float hh = sigf(zo)*tanhfast(cc);
        s.c[tid]=cc; s.h[tid]=hh;
        ws[OFF_HOUT + t*100 + tid] = hh;
      }
      if (ii>=0 && ii<5) s.prev[ii] = __expf(nraw - s.M)/s.S;
      __syncthreads();
    }
  } else {
    // =========== WORKER ===========
    WrkS& s = sm.w;
    const int w = bid-1;
    for (int i=tid;i<CHK*100;i+=512) s.w1[i]  = ws[OFF_W1DT + w*CHK*100 + i];
    for (int i=tid;i<CHK*200;i+=512) s.enc[i] = ws[OFF_ENC  + w*CHK*200 + i];
    if (tid<100) s.av[tid]=av[tid];
    __syncthreads();

    for (int t=0;t<TLEN;++t){
      { // wait for query (own spread flag copy)
        int seen = tid? 1 : 0;
        do {
          if (!seen) seen = (aldi(qflg + w*32) >= t+1);
        } while (__syncthreads_count(seen) < 512);
      }
      if (tid<100) s.a23[tid] = aldf(ws+OFF_QA+(t&1)*128+tid);
      __syncthreads();
      { // scores for own rows: 16 lanes per row
        int r=tid>>4, l=tid&15;
        float acc=0.f;
        for (int k=l;k<100;k+=16) acc += tanhfast(s.w1[r*100+k] + s.a23[k]) * s.av[k];
        acc += __shfl_xor(acc,1,16); acc += __shfl_xor(acc,2,16);
        acc += __shfl_xor(acc,4,16); acc += __shfl_xor(acc,8,16);
        if (l==0) s.srow[r]=acc;
      }
      __syncthreads();
      if (tid<CHK) astf(ws+OFF_SC+(t&1)*NN + w*CHK + tid, s.srow[tid]);
      if (tid<32){ // local softmax stats + argmax
        float v=s.srow[tid], m=v;
        for (int d=1;d<32;d<<=1) m=fmaxf(m,__shfl_xor(m,d,32));
        float e=__expf(v-m); s.e[tid]=e;
        float Ss=e;
        for (int d=1;d<32;d<<=1) Ss+=__shfl_xor(Ss,d,32);
        float bv=v; int bi=w*CHK+tid;
        for (int d=1;d<32;d<<=1){
          float ov=__shfl_xor(bv,d,32); int oi=__shfl_xor(bi,d,32);
          if (ov>bv || (ov==bv && oi<bi)){ bv=ov; bi=oi; }
        }
        if (tid==0){ s.hdr[0]=m; s.hdr[1]=Ss; s.hdr[2]=bv; ((int*)s.hdr)[3]=bi; }
      }
      __syncthreads();
      if (tid<400){ // ctx partial over own rows
        int d=tid>>1, hf=tid&1;
        float acc=0.f;
        #pragma unroll
        for (int r2=0;r2<16;r2++){ int rr=hf*16+r2; acc += s.e[rr]*s.enc[rr*200+d]; }
        acc += __shfl_xor(acc,1,2);
        if (hf==0) s.ctxp[d]=acc;
      }
      __syncthreads();
      float* rp = ws+OFF_REC+(t&1)*GW*128 + w*128;
      if (tid<100) asti((int*)rp+tid, (int)pk2(s.ctxp[2*tid], s.ctxp[2*tid+1]));
      if (tid>=100 && tid<103) astf(rp+tid, s.hdr[tid-100]);
      if (tid==103) asti((int*)rp+103, ((int*)s.hdr)[3]);
      vm0(); __syncthreads();
      if (tid==0) asti(dflg + w*32, t+1);
    }
  }
}

// ---------------- kLoss: parallel logits + log-softmax over V ----------------
__global__ __launch_bounds__(256) void kLoss(const float* outW, const float* outb,
                                             const int* oid, float* ws)
{
  const int b=blockIdx.x, tid=threadIdx.x;
  const int tile=b>>1, hf=b&1, t0=tile*16;
  __shared__ float s_hn[16*100];
  __shared__ int   s_oid[16];
  __shared__ float red[4][16][3];
  for (int i=tid;i<1600;i+=256) s_hn[i]=ws[OFF_HOUT + t0*100 + i];
  if (tid<16) s_oid[tid]=oid[t0+tid];
  __syncthreads();
  const int VSPLIT = 25129;
  int vbeg = hf? VSPLIT : 0;
  int vend = hf? VOC : VSPLIT;
  float rm[16], rs[16], ol[16];
  #pragma unroll
  for (int tt=0;tt<16;tt++){ rm[tt]=-1e30f; rs[tt]=0.f; ol[tt]=-1e30f; }
  for (int v=vbeg+tid; v<vend; v+=256){
    const float4* wr = (const float4*)(outW + (size_t)v*100);
    float acc[16];
    #pragma unroll
    for (int tt=0;tt<16;tt++) acc[tt]=0.f;
    #pragma unroll 5
    for (int q=0;q<25;q++){
      float4 wv = wr[q];
      #pragma unroll
      for (int tt=0;tt<16;tt++){
        float4 hv = *(const float4*)(s_hn + tt*100 + q*4);
        acc[tt] += wv.x*hv.x + wv.y*hv.y + wv.z*hv.z + wv.w*hv.w;
      }
    }
    float bb = outb[v];
    #pragma unroll
    for (int tt=0;tt<16;tt++){
      float lg = acc[tt] + bb;
      if (v == s_oid[tt]) ol[tt] = fmaxf(ol[tt], lg);
      if (lg <= rm[tt]) rs[tt] += __expf(lg - rm[tt]);
      else { rs[tt] = rs[tt]*__expf(rm[tt]-lg) + 1.0f; rm[tt]=lg; }
    }
  }
  int wv2=tid>>6, ln=tid&63;
  #pragma unroll
  for (int tt=0;tt<16;tt++){
    float m=rm[tt], sv=rs[tt], o=ol[tt];
    for (int d=1;d<64;d<<=1){
      float om=__shfl_xor(m,d,64), os=__shfl_xor(sv,d,64), oo=__shfl_xor(o,d,64);
      float M2=fmaxf(m,om);
      sv = sv*__expf(m-M2) + os*__expf(om-M2);
      m=M2; o=fmaxf(o,oo);
    }
    if (ln==0){ red[wv2][tt][0]=m; red[wv2][tt][1]=sv; red[wv2][tt][2]=o; }
  }
  __syncthreads();
  if (tid<16){
    float M=-1e30f;
    for (int q=0;q<4;q++) M=fmaxf(M,red[q][tid][0]);
    float S=0.f, O=-1e30f;
    for (int q=0;q<4;q++){ S += red[q][tid][1]*__expf(red[q][tid][0]-M); O=fmaxf(O,red[q][tid][2]); }
    float* pb = ws + OFF_PB + (((tile*2)+hf)*16 + tid)*4;
    pb[0]=M; pb[1]=S; pb[2]=O;
  }
}

// ---------------- kFinal: combine halves, sum, scale ----------------
__global__ void kFinal(const float* weight, float* ws, float* out){
  __shared__ float red[256];
  int tid=threadIdx.x;
  float acc=0.f;
  for (int t=tid;t<TLEN;t+=256){
    int tile=t>>4, tt=t&15;
    const float* p0 = ws + OFF_PB + ((tile*2+0)*16+tt)*4;
    const float* p1 = ws + OFF_PB + ((tile*2+1)*16+tt)*4;
    float M=fmaxf(p0[0],p1[0]);
    float S=p0[1]*__expf(p0[0]-M) + p1[1]*__expf(p1[0]-M);
    float O=fmaxf(p0[2],p1[2]);
    acc += (M + logf(S)) - O;    // lt = lse - logit[oid]
  }
  red[tid]=acc; __syncthreads();
  for (int d=128; d>0; d>>=1){
    if (tid<d) red[tid]+=red[tid+d];
    __syncthreads();
  }
  if (tid==0) out[0]=red[0]*weight[0];
}

// ---------------- launch ----------------
extern "C" void kernel_launch(void* const* d_in, const int* in_sizes, int n_in,
                              void* d_out, int out_size, void* d_ws, size_t ws_size,
                              hipStream_t stream) {
  const int*   src      = (const int*)  d_in[0];
  const int*   tag      = (const int*)  d_in[1];
  const int*   oid      = (const int*)  d_in[2];
  const float* weight   = (const float*)d_in[3];
  const float* emb_char = (const float*)d_in[4];
  const float* emb_tag  = (const float*)d_in[5];
  const float* fWih=(const float*)d_in[6],  *fWhh=(const float*)d_in[7],  *fb=(const float*)d_in[8];
  const float* bWih=(const float*)d_in[9],  *bWhh=(const float*)d_in[10], *bb=(const float*)d_in[11];
  const float* tWih=(const float*)d_in[12], *tWhh=(const float*)d_in[13], *tb=(const float*)d_in[14];
  const float* dWih=(const float*)d_in[15], *dWhh=(const float*)d_in[16], *db=(const float*)d_in[17];
  const float* aw1 =(const float*)d_in[18], *aw2=(const float*)d_in[19];
  const float* aw3 =(const float*)d_in[20], *av =(const float*)d_in[21];
  const float* taw1=(const float*)d_in[22], *taw2=(const float*)d_in[23], *tavv=(const float*)d_in[24];
  const float* outW=(const float*)d_in[25], *outb=(const float*)d_in[26];
  float* ws  = (float*)d_ws;
  float* out = (float*)d_out;

  kInit<<<1,256,0,stream>>>(ws);
  kPrep<<<2*NN+TTAG+TLEN, 512, 0, stream>>>(src,tag,oid,emb_char,emb_tag,
                                            fWih,fb,bWih,bb,tWih,tb,dWih,db,ws);
  kEnc<<<3,512,0,stream>>>(fWhh,bWhh,tWhh,taw1,dWih,ws);
  kMid<<<NN,128,0,stream>>>(aw1,ws);
  kDec<<<1+GW,512,0,stream>>>(dWhh,dWih,aw2,aw3,av,taw2,tavv,ws);
  kLoss<<<256,256,0,stream>>>(outW,outb,oid,ws);
  kFinal<<<1,256,0,stream>>>(weight,ws,out);
}